// Round 19
// baseline (796.564 us; speedup 1.0000x reference)
//
#include <hip/hip_runtime.h>
#include <float.h>

#define KC 4096
#define DIM 256
#define MB 16384            // m per batch element (16*32*32)
#define NTOT 65536          // rows
#define ZELEMS 16777216
#define LOSS_OFF 16777216
#define IDX_OFF  16777217
// TAU: 2*(grid ULP(256)=3.05e-5) + 2*fp16-chain score err (<=4.7e-5 worst) + slack.
// Validated empirically at 1.5e-4 in R11-R18 (0 misses across 65536 rows).
#define TAU 1.5e-4f

// scratch inside z_q output region (fully overwritten by vq_apply at the end):
// [0, 524288)       fp16 e' A-fragment table (2MB)
#define BT_OFF   524288     // f32 |e_k|^2 table, 4096 floats
#define CNT_OFF  528400     // 2 uints (cand count, full count)
#define CAND_OFF 532480     // uint4 entries (16B each), cap 65536
#define FULL_OFF 800000     // uint entries, cap 65536

typedef _Float16 h8 __attribute__((ext_vector_type(8)));
typedef float f4v __attribute__((ext_vector_type(4)));

__device__ __forceinline__ bool lexlt(float av, int ai, float bv, int bi) {
    return (av < bv) || (av == bv && ai < bi);
}

// exact merge of two sorted top-3 sets; indices kept for slots 1,2 only.
// (R12-validated.)
__device__ __forceinline__ void merge3(float& b1, int& i1, float& b2, int& i2, float& b3,
                                       float c1, int j1, float c2, int j2, float c3) {
    bool aw = (b1 < c1) || (b1 == c1 && i1 < j1);
    float x1 = aw ? b1 : c1; int xi1 = aw ? i1 : j1;
    float x2 = aw ? b2 : c2; int xi2 = aw ? i2 : j2;
    float x3 = aw ? b3 : c3;
    float y1 = aw ? c1 : b1; int yi1 = aw ? j1 : i1;
    float y2 = aw ? c2 : b2;
    bool s2 = (x2 < y1) || (x2 == y1 && xi2 < yi1);
    float o2 = s2 ? x2 : y1; int oi2 = s2 ? xi2 : yi1;
    float o3 = s2 ? fminf(x3, y1) : fminf(x2, y2);
    b1 = x1; i1 = xi1; b2 = o2; i2 = oi2; b3 = o3;
}

// ---- P: fused prep. Blocks 0-511: fp16 e'=e*4096 A-frag table (R10-R18
// verified geometry). Blocks 512-1535: |e|^2 (fp64->f32), one wave per code. ----
__global__ __launch_bounds__(256) void vq_prep(const float* __restrict__ e,
                                               float* __restrict__ out) {
    if (blockIdx.x < 512) {
        int t = blockIdx.x * 256 + threadIdx.x;        // 0..131071
        int code = t >> 5, s8 = t & 31;
        const float4* src = reinterpret_cast<const float4*>(e + (size_t)code * DIM + s8 * 8);
        float4 v0 = src[0], v1 = src[1];
        float f[8] = {v0.x, v0.y, v0.z, v0.w, v1.x, v1.y, v1.z, v1.w};
        union { uint4 q; _Float16 h[8]; } P;
        #pragma unroll
        for (int p = 0; p < 8; ++p) P.h[p] = (_Float16)(f[p] * 4096.0f);
        int kc = s8 >> 2, khi = s8 & 3;
        int lane = khi * 16 + (code & 15);
        int slot = ((code >> 4) * 8 + kc) * 64 + lane;
        reinterpret_cast<uint4*>(out)[slot] = P.q;
    } else {
        int k = (blockIdx.x - 512) * 4 + (threadIdx.x >> 6);   // 0..4095
        int lane = threadIdx.x & 63;
        float4 v = reinterpret_cast<const float4*>(e + (size_t)k * DIM)[lane];
        double s = (double)v.x * v.x + (double)v.y * v.y + (double)v.z * v.z + (double)v.w * v.w;
        #pragma unroll
        for (int off = 32; off > 0; off >>= 1) s += __shfl_down(s, off);
        if (lane == 0) out[BT_OFF + k] = (float)s;
    }
}

// SEL4: fold 4 tile scores into sorted-3 state (values b1<=b2<=b3, indices
// for slots 1,2). Plain value compares only — any tie reaching b1/b2 makes
// b2<=b1+TAU -> row auto-flagged -> exact resolvers decide (tie-safe).
#define SEL4(S0, S1, S2, S3, KB, B1, I1, B2, I2, B3)                             \
{                                                                                \
    float lo01 = fminf(S0, S1), hi01 = fmaxf(S0, S1);                            \
    float lo23 = fminf(S2, S3), hi23 = fmaxf(S2, S3);                            \
    float m1 = fminf(lo01, lo23);                                                \
    float m2 = fminf(fmaxf(lo01, lo23), fminf(hi01, hi23));                      \
    if (m1 < B3) {                                                               \
        int j1 = (S0 == m1) ? (KB) : ((S1 == m1) ? (KB + 1)                      \
                 : ((S2 == m1) ? (KB + 2) : (KB + 3)));                          \
        int j2 = (S0 == m2 && (KB) != j1) ? (KB)                                 \
                 : ((S1 == m2 && (KB + 1) != j1) ? (KB + 1)                      \
                 : ((S2 == m2 && (KB + 2) != j1) ? (KB + 2) : (KB + 3)));        \
        bool c = m1 < B1;                                                        \
        bool a2 = m1 < B2;             /* pathA: m1 >= B1 */                     \
        float A2v = a2 ? m1 : B2;  int A2i = a2 ? j1 : I2;                       \
        float A3v = a2 ? fminf(B2, m2) : fminf(B3, m1);                          \
        bool bw = m2 < B1;             /* pathB: m1 < B1 */                      \
        float Bv2 = bw ? m2 : B1;  int Bi2 = bw ? j2 : I1;                       \
        float Bv3 = bw ? B1 : fminf(B2, m2);                                     \
        B3 = c ? Bv3 : A3v;                                                      \
        B2 = c ? Bv2 : A2v;  I2 = c ? Bi2 : A2i;                                 \
        B1 = c ? m1 : B1;    I1 = c ? j1 : I1;                                   \
    }                                                                            \
}

// ---- K1: fp16 MFMA, single-pass sorted-3 selection. Block = 128 rows
// (4 waves x 32 rows, 2 row-sets/wave). 4 independent MFMA chains
// (kc even/odd x set). Classes: b2>thr clean; b3>thr cand{I1,I2}; else full.
__global__ __launch_bounds__(256) void vq_fast(const float* __restrict__ z,
                                               float* __restrict__ out) {
    __shared__ uint4 etile[2][512];                // 16KB double-buffered tile
    const int tid = threadIdx.x;
    const int wave = tid >> 6, lane = tid & 63;
    const int khi = lane >> 4, l16 = lane & 15;
    const int nbase = blockIdx.x * 128;
    const int b = nbase / MB;
    const int mbase = nbase % MB;
    const float* zb = z + (size_t)b * DIM * MB + mbase + wave * 32 + l16;

    // z B-fragments (fp16), 2 row-sets x 8 kc
    h8 zf0[8], zf1[8];
    #pragma unroll
    for (int kc = 0; kc < 8; ++kc) {
        h8 va, vb;
        #pragma unroll
        for (int j = 0; j < 8; ++j) {
            size_t off = (size_t)(kc * 32 + khi * 8 + j) * MB;
            va[j] = (_Float16)zb[off];
            vb[j] = (_Float16)zb[off + 16];
        }
        zf0[kc] = va; zf1[kc] = vb;
    }

    const uint4* ET = reinterpret_cast<const uint4*>(out);
    const float* Btab = out + BT_OFF;

    float b10 = FLT_MAX, b20 = FLT_MAX, b30 = FLT_MAX;
    float b11 = FLT_MAX, b21 = FLT_MAX, b31 = FLT_MAX;
    int i10 = 0, i20 = 0, i11 = 0, i21 = 0;

    uint4 r0 = ET[tid], r1 = ET[tid + 256];        // preload tile 0
    for (int tile = 0; tile < KC / 16; ++tile) {
        const int cur = tile & 1;
        etile[cur][tid] = r0; etile[cur][tid + 256] = r1;
        __syncthreads();                           // only barrier per tile
        if (tile < KC / 16 - 1) {
            r0 = ET[(size_t)(tile + 1) * 512 + tid];
            r1 = ET[(size_t)(tile + 1) * 512 + tid + 256];
        }

        f4v a0e = {0.f, 0.f, 0.f, 0.f}, a0o = a0e, a1e = a0e, a1o = a0e;
        #pragma unroll
        for (int kc = 0; kc < 8; kc += 2) {
            union { uint4 q; h8 v; } afe, afo;
            afe.q = etile[cur][kc * 64 + lane];
            afo.q = etile[cur][(kc + 1) * 64 + lane];
            a0e = __builtin_amdgcn_mfma_f32_16x16x32_f16(afe.v, zf0[kc], a0e, 0, 0, 0);
            a1e = __builtin_amdgcn_mfma_f32_16x16x32_f16(afe.v, zf1[kc], a1e, 0, 0, 0);
            a0o = __builtin_amdgcn_mfma_f32_16x16x32_f16(afo.v, zf0[kc + 1], a0o, 0, 0, 0);
            a1o = __builtin_amdgcn_mfma_f32_16x16x32_f16(afo.v, zf1[kc + 1], a1o, 0, 0, 0);
        }

        const f4v Bv = *reinterpret_cast<const f4v*>(Btab + tile * 16 + khi * 4);
        const int kb = tile * 16 + khi * 4;
        float s0[4], s1[4];
        #pragma unroll
        for (int i = 0; i < 4; ++i) {
            s0[i] = fmaf(-4.8828125e-4f, a0e[i] + a0o[i], Bv[i]);  // -1/2048 exact
            s1[i] = fmaf(-4.8828125e-4f, a1e[i] + a1o[i], Bv[i]);
        }
        SEL4(s0[0], s0[1], s0[2], s0[3], kb, b10, i10, b20, i20, b30)
        SEL4(s1[0], s1[1], s1[2], s1[3], kb, b11, i11, b21, i21, b31)
    }

    // merge sorted-3 across the 4 khi groups (lex; R12-validated merge3)
    #pragma unroll
    for (int off = 16; off < 64; off <<= 1) {
        merge3(b10, i10, b20, i20, b30,
               __shfl_xor(b10, off), __shfl_xor(i10, off),
               __shfl_xor(b20, off), __shfl_xor(i20, off), __shfl_xor(b30, off));
        merge3(b11, i11, b21, i21, b31,
               __shfl_xor(b11, off), __shfl_xor(i11, off),
               __shfl_xor(b21, off), __shfl_xor(i21, off), __shfl_xor(b31, off));
    }

    // classify + emit (lanes<16 own one row per set)
    unsigned* cntg = (unsigned*)(out + CNT_OFF);
    #pragma unroll
    for (int set = 0; set < 2; ++set) {
        bool act = (lane < 16);
        int gidx = nbase + wave * 32 + set * 16 + l16;
        float B1 = set ? b11 : b10, B2 = set ? b21 : b20, B3 = set ? b31 : b30;
        int I1 = set ? i11 : i10, I2 = set ? i21 : i20;
        float thr = B1 + TAU;
        bool clean = (B2 > thr);
        bool cand = act && !clean && (B3 > thr);
        bool full = act && !clean && !cand;
        if (act) out[IDX_OFF + gidx] = (float)I1;  // final for clean; placeholder else
        unsigned long long mc = __ballot(cand);
        if (mc) {
            int leader = __ffsll((long long)mc) - 1;
            unsigned base = 0;
            if (lane == leader) base = atomicAdd(cntg, (unsigned)__popcll(mc));
            base = __shfl(base, leader);
            if (cand) {
                unsigned pos = base + (unsigned)__popcll(mc & ((1ull << lane) - 1ull));
                reinterpret_cast<uint4*>(out + CAND_OFF)[pos] =
                    make_uint4((unsigned)gidx,
                               (unsigned)I1 | ((unsigned)I2 << 16),
                               (unsigned)I1 | ((unsigned)I1 << 16), 0u);
            }
        }
        unsigned long long mf = __ballot(full);
        if (mf) {
            int leader = __ffsll((long long)mf) - 1;
            unsigned base = 0;
            if (lane == leader) base = atomicAdd(cntg + 1, (unsigned)__popcll(mf));
            base = __shfl(base, leader);
            if (full) {
                unsigned pos = base + (unsigned)__popcll(mf & ((1ull << lane) - 1ull));
                reinterpret_cast<unsigned*>(out + FULL_OFF)[pos] = (unsigned)gidx;
            }
        }
    }
}

// ---- K2a: candidate rescore (<=4 codes), B from Btab, grid-stride waves ----
__global__ __launch_bounds__(256) void vq_resolve_cand(const float* __restrict__ z,
                                                       const float* __restrict__ e,
                                                       float* __restrict__ out) {
    const int wave = threadIdx.x >> 6, lane = threadIdx.x & 63;
    const unsigned n = *reinterpret_cast<const unsigned*>(out + CNT_OFF);
    const uint4* list = reinterpret_cast<const uint4*>(out + CAND_OFF);
    const float* Btab = out + BT_OFF;
    for (unsigned ei = blockIdx.x * 4 + wave; ei < n; ei += gridDim.x * 4) {
        uint4 ent = list[ei];
        const int gidx = (int)ent.x;
        const int c1 = (int)(ent.y & 0xFFFFu), c2 = (int)(ent.y >> 16);
        const int c3 = (int)(ent.z & 0xFFFFu), c4 = (int)(ent.z >> 16);
        const int b = gidx >> 14, m = gidx & (MB - 1);
        const float* zr = z + (size_t)b * DIM * MB + m;
        const float* e1 = e + (size_t)c1 * DIM;
        const float* e2 = e + (size_t)c2 * DIM;
        const float* e3 = e + (size_t)c3 * DIM;
        const float* e4 = e + (size_t)c4 * DIM;
        double A = 0.0;
        double d1 = 0.0, d2 = 0.0, d3 = 0.0, d4 = 0.0;
        #pragma unroll
        for (int jj = 0; jj < 4; ++jj) {
            int d = lane * 4 + jj;
            double zv = (double)zr[(size_t)d * MB];
            A = fma(zv, zv, A);
            d1 = fma(zv, (double)e1[d], d1);
            d2 = fma(zv, (double)e2[d], d2);
            d3 = fma(zv, (double)e3[d], d3);
            d4 = fma(zv, (double)e4[d], d4);
        }
        #pragma unroll
        for (int mm = 1; mm < 64; mm <<= 1) {
            A += __shfl_xor(A, mm);
            d1 += __shfl_xor(d1, mm); d2 += __shfl_xor(d2, mm);
            d3 += __shfl_xor(d3, mm); d4 += __shfl_xor(d4, mm);
        }
        if (lane == 0) {
            float Af = (float)A;
            float s1 = (Af - (float)(2.0 * d1)) + Btab[c1];
            float s2 = (Af - (float)(2.0 * d2)) + Btab[c2];
            float s3 = (Af - (float)(2.0 * d3)) + Btab[c3];
            float s4 = (Af - (float)(2.0 * d4)) + Btab[c4];
            float bv = s1; int bk = c1;
            if (lexlt(s2, c2, bv, bk)) { bv = s2; bk = c2; }
            if (lexlt(s3, c3, bv, bk)) { bv = s3; bk = c3; }
            if (lexlt(s4, c4, bv, bk)) { bv = s4; bk = c4; }
            out[IDX_OFF + gidx] = (float)bk;
        }
    }
}

// ---- K2b: full exact rescan, B from Btab, grid-stride blocks ----
__global__ __launch_bounds__(256) void vq_resolve_full(const float* __restrict__ z,
                                                       const float* __restrict__ e,
                                                       float* __restrict__ out) {
    __shared__ float zs[DIM];
    __shared__ float rv[4];
    __shared__ int ri[4];
    const int tid = threadIdx.x;
    const int wave = tid >> 6, lane = tid & 63;
    const unsigned n = reinterpret_cast<const unsigned*>(out + CNT_OFF)[1];
    const unsigned* list = reinterpret_cast<const unsigned*>(out + FULL_OFF);
    const float* Btab = out + BT_OFF;
    for (unsigned ei = blockIdx.x; ei < n; ei += gridDim.x) {
        const int gidx = (int)list[ei];
        const int b = gidx >> 14, m = gidx & (MB - 1);
        const float* zr = z + (size_t)b * DIM * MB + m;
        if (tid < DIM) zs[tid] = zr[(size_t)tid * MB];
        __syncthreads();
        double av = 0.0;
        #pragma unroll
        for (int t2 = 0; t2 < 4; ++t2) {
            double zv = (double)zs[lane * 4 + t2];
            av = fma(zv, zv, av);
        }
        #pragma unroll
        for (int mm = 1; mm < 64; mm <<= 1) av += __shfl_xor(av, mm);
        const float Af = (float)av;

        float bsv = FLT_MAX; int bsk = 0;
        for (int kk = 0; kk < 16; ++kk) {
            const int k = kk * 256 + tid;          // ascending per thread
            const float4* er4 = reinterpret_cast<const float4*>(e + (size_t)k * DIM);
            const float4* zs4 = reinterpret_cast<const float4*>(zs);
            double dot0 = 0.0, dot1 = 0.0;
            #pragma unroll 8
            for (int d4 = 0; d4 < 64; ++d4) {
                float4 ev = er4[d4];
                float4 zv = zs4[d4];
                dot0 = fma((double)zv.x, (double)ev.x, dot0);
                dot1 = fma((double)zv.y, (double)ev.y, dot1);
                dot0 = fma((double)zv.z, (double)ev.z, dot0);
                dot1 = fma((double)zv.w, (double)ev.w, dot1);
            }
            float s = (Af - (float)(2.0 * (dot0 + dot1))) + Btab[k];
            if (s < bsv) { bsv = s; bsk = k; }
        }
        #pragma unroll
        for (int mm = 1; mm < 64; mm <<= 1) {
            float ov = __shfl_xor(bsv, mm);
            int oi = __shfl_xor(bsk, mm);
            if (ov < bsv || (ov == bsv && oi < bsk)) { bsv = ov; bsk = oi; }
        }
        if (lane == 0) { rv[wave] = bsv; ri[wave] = bsk; }
        __syncthreads();
        if (tid == 0) {
            float bv = rv[0]; int bk = ri[0];
            #pragma unroll
            for (int wv = 1; wv < 4; ++wv) {
                if (rv[wv] < bv || (rv[wv] == bv && ri[wv] < bk)) { bv = rv[wv]; bk = ri[wv]; }
            }
            out[IDX_OFF + gidx] = (float)bk;
        }
        __syncthreads();
    }
}

// ---- K3: z_q scatter + fused loss; e-rows staged in LDS (R12-proven) ----
__global__ __launch_bounds__(256) void vq_apply(const float* __restrict__ z,
                                                const float* __restrict__ e,
                                                float* __restrict__ out) {
    __shared__ int lds_fi[64];
    __shared__ float lds_e[64][260];
    __shared__ double lds_ls[4];
    const int tid = threadIdx.x;
    const int wave = tid >> 6, lane = tid & 63;
    const int nbase = blockIdx.x * 64;
    const int b = nbase / MB;
    const int mbase = nbase % MB;
    if (tid < 64) lds_fi[tid] = (int)out[IDX_OFF + nbase + tid];
    __syncthreads();
    for (int r = wave; r < 64; r += 4) {
        int code = lds_fi[r];
        float4 v = reinterpret_cast<const float4*>(e + (size_t)code * DIM)[lane];
        *reinterpret_cast<float4*>(&lds_e[r][lane * 4]) = v;
    }
    __syncthreads();

    double lsum = 0.0;
    const int mloc = tid & 63;
    const int d0 = tid >> 6;
    #pragma unroll 4
    for (int d = d0; d < DIM; d += 4) {
        float ev = lds_e[mloc][d];
        size_t off = (size_t)b * (DIM * MB) + (size_t)d * MB + mbase + mloc;
        float zv = z[off];
        out[off] = ev;
        float diff = ev - zv;
        lsum += (double)diff * diff;
    }
    #pragma unroll
    for (int off = 32; off > 0; off >>= 1) lsum += __shfl_down(lsum, off);
    if (lane == 0) lds_ls[wave] = lsum;
    __syncthreads();
    if (tid == 0) {
        double t = lds_ls[0] + lds_ls[1] + lds_ls[2] + lds_ls[3];
        atomicAdd(out + LOSS_OFF, (float)(t * (1.25 / (double)ZELEMS)));
    }
}

extern "C" void kernel_launch(void* const* d_in, const int* in_sizes, int n_in,
                              void* d_out, int out_size, void* d_ws, size_t ws_size,
                              hipStream_t stream) {
    const float* z = (const float*)d_in[0];    // [4,256,16,32,32] fp32
    const float* e = (const float*)d_in[1];    // [4096,256] fp32
    float* out = (float*)d_out;

    hipMemsetAsync(out + LOSS_OFF, 0, sizeof(float), stream);
    hipMemsetAsync(out + CNT_OFF, 0, 2 * sizeof(unsigned), stream);
    vq_prep<<<1536, 256, 0, stream>>>(e, out);
    vq_fast<<<NTOT / 128, 256, 0, stream>>>(z, out);
    vq_resolve_cand<<<1024, 256, 0, stream>>>(z, e, out);
    vq_resolve_full<<<512, 256, 0, stream>>>(z, e, out);
    vq_apply<<<NTOT / 64, 256, 0, stream>>>(z, e, out);
}

// Round 20
// 523.435 us; speedup vs baseline: 1.5218x; 1.5218x over previous
//
#include <hip/hip_runtime.h>
#include <float.h>

#define KC 4096
#define DIM 256
#define MB 16384            // m per batch element (16*32*32)
#define NTOT 65536          // rows
#define ZELEMS 16777216
#define LOSS_OFF 16777216
#define IDX_OFF  16777217
// TAU: 2*(grid ULP(256)=3.05e-5) + 2*fp16-chain score err (<=4.7e-5 worst) + slack.
// Validated empirically at 1.5e-4 in R11-R19 (0 misses across 65536 rows).
#define TAU 1.5e-4f

// scratch inside z_q output region (fully overwritten by vq_apply at the end):
// [0, 524288)       fp16 e' A-fragment table (2MB)
#define BT_OFF   524288     // f32 |e_k|^2 table, 4096 floats
#define CNT_OFF  528400     // 2 uints (cand count, full count)
#define CAND_OFF 532480     // uint4 entries (16B each), cap 65536
#define FULL_OFF 800000     // uint entries, cap 65536

typedef _Float16 h8 __attribute__((ext_vector_type(8)));
typedef float f4v __attribute__((ext_vector_type(4)));

__device__ __forceinline__ bool lexlt(float av, int ai, float bv, int bi) {
    return (av < bv) || (av == bv && ai < bi);
}

// ---- P: fused prep. Blocks 0-511: fp16 e'=e*4096 A-frag table (R10-R19
// verified geometry). Blocks 512-1535: |e|^2 (fp64->f32), one wave per code. ----
__global__ __launch_bounds__(256) void vq_prep(const float* __restrict__ e,
                                               float* __restrict__ out) {
    if (blockIdx.x < 512) {
        int t = blockIdx.x * 256 + threadIdx.x;        // 0..131071
        int code = t >> 5, s8 = t & 31;
        const float4* src = reinterpret_cast<const float4*>(e + (size_t)code * DIM + s8 * 8);
        float4 v0 = src[0], v1 = src[1];
        float f[8] = {v0.x, v0.y, v0.z, v0.w, v1.x, v1.y, v1.z, v1.w};
        union { uint4 q; _Float16 h[8]; } P;
        #pragma unroll
        for (int p = 0; p < 8; ++p) P.h[p] = (_Float16)(f[p] * 4096.0f);
        int kc = s8 >> 2, khi = s8 & 3;
        int lane = khi * 16 + (code & 15);
        int slot = ((code >> 4) * 8 + kc) * 64 + lane;
        reinterpret_cast<uint4*>(out)[slot] = P.q;
    } else {
        int k = (blockIdx.x - 512) * 4 + (threadIdx.x >> 6);   // 0..4095
        int lane = threadIdx.x & 63;
        float4 v = reinterpret_cast<const float4*>(e + (size_t)k * DIM)[lane];
        double s = (double)v.x * v.x + (double)v.y * v.y + (double)v.z * v.z + (double)v.w * v.w;
        #pragma unroll
        for (int off = 32; off > 0; off >>= 1) s += __shfl_down(s, off);
        if (lane == 0) out[BT_OFF + k] = (float)s;
    }
}

// sorted insert keeping the 4 SMALLEST pushed (v0<=v1<=v2<=v3); exact-loss
// guarantee (R18-validated): any evicted value >= v3, so a lost window member
// forces v3<=thr -> n=5 -> full. No overflow counter needed.
#define INS4(V0, V1, V2, V3, L0, L1, L2, L3, v, k)                              \
    if (v < V3) {                                                               \
        if (v < V2) {                                                           \
            V3 = V2; L3 = L2;                                                   \
            if (v < V1) {                                                       \
                V2 = V1; L2 = L1;                                               \
                if (v < V0) { V1 = V0; L1 = L0; V0 = v; L0 = k; }               \
                else        { V1 = v; L1 = k; }                                 \
            } else { V2 = v; L2 = k; }                                          \
        } else { V3 = v; L3 = k; }                                              \
    }

// ---- K1: fp16 MFMA (4 indep chains), single-pass exact-window (R18
// classifier). Block = 128 rows (4 waves x 32 rows, 2 row-sets/wave). ----
__global__ __launch_bounds__(256) void vq_fast(const float* __restrict__ z,
                                               float* __restrict__ out) {
    __shared__ uint4 etile[2][512];                // 16KB double-buffered tile
    __shared__ unsigned long long lists[4][32][4]; // (wave,row,khi) packed lists
    const int tid = threadIdx.x;
    const int wave = tid >> 6, lane = tid & 63;
    const int khi = lane >> 4, l16 = lane & 15;
    const int nbase = blockIdx.x * 128;
    const int b = nbase / MB;
    const int mbase = nbase % MB;
    const float* zb = z + (size_t)b * DIM * MB + mbase + wave * 32 + l16;

    // z B-fragments (fp16), 2 row-sets x 8 kc
    h8 zf0[8], zf1[8];
    #pragma unroll
    for (int kc = 0; kc < 8; ++kc) {
        h8 va, vb;
        #pragma unroll
        for (int j = 0; j < 8; ++j) {
            size_t off = (size_t)(kc * 32 + khi * 8 + j) * MB;
            va[j] = (_Float16)zb[off];
            vb[j] = (_Float16)zb[off + 16];
        }
        zf0[kc] = va; zf1[kc] = vb;
    }

    const uint4* ET = reinterpret_cast<const uint4*>(out);
    const float* Btab = out + BT_OFF;

    float b10 = FLT_MAX, b11 = FLT_MAX;
    int bk0 = 0, bk1 = 0;
    float v00 = FLT_MAX, v01 = FLT_MAX, v02 = FLT_MAX, v03 = FLT_MAX;
    float v10 = FLT_MAX, v11 = FLT_MAX, v12 = FLT_MAX, v13 = FLT_MAX;
    int l00 = 0, l01 = 0, l02 = 0, l03 = 0;
    int l10 = 0, l11 = 0, l12 = 0, l13 = 0;

    uint4 r0 = ET[tid], r1 = ET[tid + 256];        // preload tile 0
    for (int tile = 0; tile < KC / 16; ++tile) {
        const int cur = tile & 1;
        etile[cur][tid] = r0; etile[cur][tid + 256] = r1;
        __syncthreads();                           // only barrier per tile
        if (tile < KC / 16 - 1) {
            r0 = ET[(size_t)(tile + 1) * 512 + tid];
            r1 = ET[(size_t)(tile + 1) * 512 + tid + 256];
        }

        // 4 independent MFMA chains (kc even/odd x 2 row-sets) for ILP
        f4v a0e = {0.f, 0.f, 0.f, 0.f}, a0o = a0e, a1e = a0e, a1o = a0e;
        #pragma unroll
        for (int kc = 0; kc < 8; kc += 2) {
            union { uint4 q; h8 v; } afe, afo;
            afe.q = etile[cur][kc * 64 + lane];
            afo.q = etile[cur][(kc + 1) * 64 + lane];
            a0e = __builtin_amdgcn_mfma_f32_16x16x32_f16(afe.v, zf0[kc], a0e, 0, 0, 0);
            a1e = __builtin_amdgcn_mfma_f32_16x16x32_f16(afe.v, zf1[kc], a1e, 0, 0, 0);
            a0o = __builtin_amdgcn_mfma_f32_16x16x32_f16(afo.v, zf0[kc + 1], a0o, 0, 0, 0);
            a1o = __builtin_amdgcn_mfma_f32_16x16x32_f16(afo.v, zf1[kc + 1], a1o, 0, 0, 0);
        }

        const f4v Bv = *reinterpret_cast<const f4v*>(Btab + tile * 16 + khi * 4);
        const int kb = tile * 16 + khi * 4;
        float sc0[4], sc1[4];
        #pragma unroll
        for (int i = 0; i < 4; ++i) {
            sc0[i] = fmaf(-4.8828125e-4f, a0e[i] + a0o[i], Bv[i]);  // -1/2048 exact
            sc1[i] = fmaf(-4.8828125e-4f, a1e[i] + a1o[i], Bv[i]);
        }
        float m0 = fminf(fminf(sc0[0], sc0[1]), fminf(sc0[2], sc0[3]));
        if (m0 <= b10 + TAU) {                     // rare: detail insert
            #pragma unroll
            for (int i = 0; i < 4; ++i) {
                float s = sc0[i]; int k = kb + i;  // ascending k per lane
                if (s < b10) {
                    if (b10 <= s + TAU) INS4(v00, v01, v02, v03, l00, l01, l02, l03, b10, bk0)
                    b10 = s; bk0 = k;
                } else if (s <= b10 + TAU) {
                    INS4(v00, v01, v02, v03, l00, l01, l02, l03, s, k)
                }
            }
        }
        float m1 = fminf(fminf(sc1[0], sc1[1]), fminf(sc1[2], sc1[3]));
        if (m1 <= b11 + TAU) {
            #pragma unroll
            for (int i = 0; i < 4; ++i) {
                float s = sc1[i]; int k = kb + i;
                if (s < b11) {
                    if (b11 <= s + TAU) INS4(v10, v11, v12, v13, l10, l11, l12, l13, b11, bk1)
                    b11 = s; bk1 = k;
                } else if (s <= b11 + TAU) {
                    INS4(v10, v11, v12, v13, l10, l11, l12, l13, s, k)
                }
            }
        }
    }

    // merge top-1 across the 4 khi groups (lex), keep own (b1,bk) intact
    float gb0 = b10, gb1 = b11;
    int gk0 = bk0, gk1 = bk1;
    #pragma unroll
    for (int off = 16; off < 64; off <<= 1) {
        float ov = __shfl_xor(gb0, off); int ok = __shfl_xor(gk0, off);
        if (lexlt(ov, ok, gb0, gk0)) { gb0 = ov; gk0 = ok; }
        ov = __shfl_xor(gb1, off); ok = __shfl_xor(gk1, off);
        if (lexlt(ov, ok, gb1, gk1)) { gb1 = ov; gk1 = ok; }
    }
    const float thr0 = gb0 + TAU, thr1 = gb1 + TAU;

    // exact-filter own entries vs FINAL threshold, pack (<=4 ks + count<=5)
    int n0 = 0, pa0 = 0, pb0 = 0, pc0 = 0, pd0 = 0;
    #define ADD0(kk) { if (n0 == 0) pa0 = kk; else if (n0 == 1) pb0 = kk; \
                       else if (n0 == 2) pc0 = kk; else if (n0 == 3) pd0 = kk; n0++; }
    if (b10 <= thr0) ADD0(bk0)
    if (v00 <= thr0) ADD0(l00)
    if (v01 <= thr0) ADD0(l01)
    if (v02 <= thr0) ADD0(l02)
    if (v03 <= thr0) ADD0(l03)
    int n1 = 0, pa1 = 0, pb1 = 0, pc1 = 0, pd1 = 0;
    #define ADD1(kk) { if (n1 == 0) pa1 = kk; else if (n1 == 1) pb1 = kk; \
                       else if (n1 == 2) pc1 = kk; else if (n1 == 3) pd1 = kk; n1++; }
    if (b11 <= thr1) ADD1(bk1)
    if (v10 <= thr1) ADD1(l10)
    if (v11 <= thr1) ADD1(l11)
    if (v12 <= thr1) ADD1(l12)
    if (v13 <= thr1) ADD1(l13)
    lists[wave][l16][khi] = ((unsigned long long)n0 << 48) |
        (unsigned long long)pa0 | ((unsigned long long)pb0 << 12) |
        ((unsigned long long)pc0 << 24) | ((unsigned long long)pd0 << 36);
    lists[wave][16 + l16][khi] = ((unsigned long long)n1 << 48) |
        (unsigned long long)pa1 | ((unsigned long long)pb1 << 12) |
        ((unsigned long long)pc1 << 24) | ((unsigned long long)pd1 << 36);
    __syncthreads();

    // gather + classify + emit (lanes<16 own one row per set)
    unsigned* cntg = (unsigned*)(out + CNT_OFF);
    #pragma unroll
    for (int set = 0; set < 2; ++set) {
        bool act = (lane < 16);
        int gidx = nbase + wave * 32 + set * 16 + l16;
        int I1 = set ? gk1 : gk0;
        int tot = 0, c[4];
        c[0] = c[1] = c[2] = c[3] = I1;            // pad with best (harmless dup)
        if (act) {
            #pragma unroll
            for (int q = 0; q < 4; ++q) {
                unsigned long long pl = lists[wave][set * 16 + l16][q];
                int pc = (int)(pl >> 48);
                #pragma unroll
                for (int j = 0; j < 4; ++j) {
                    int kv = (int)((pl >> (12 * j)) & 4095ull);
                    if (j < pc && tot + j < 4) c[tot + j] = kv;
                }
                tot += pc;
            }
            out[IDX_OFF + gidx] = (float)I1;       // final for clean; placeholder else
        }
        bool cand = act && (tot >= 2) && (tot <= 4);
        bool full = act && (tot > 4);
        unsigned long long mc = __ballot(cand);
        if (mc) {
            int leader = __ffsll((long long)mc) - 1;
            unsigned base = 0;
            if (lane == leader) base = atomicAdd(cntg, (unsigned)__popcll(mc));
            base = __shfl(base, leader);
            if (cand) {
                unsigned pos = base + (unsigned)__popcll(mc & ((1ull << lane) - 1ull));
                reinterpret_cast<uint4*>(out + CAND_OFF)[pos] =
                    make_uint4((unsigned)gidx,
                               (unsigned)c[0] | ((unsigned)c[1] << 16),
                               (unsigned)c[2] | ((unsigned)c[3] << 16), 0u);
            }
        }
        unsigned long long mf = __ballot(full);
        if (mf) {
            int leader = __ffsll((long long)mf) - 1;
            unsigned base = 0;
            if (lane == leader) base = atomicAdd(cntg + 1, (unsigned)__popcll(mf));
            base = __shfl(base, leader);
            if (full) {
                unsigned pos = base + (unsigned)__popcll(mf & ((1ull << lane) - 1ull));
                reinterpret_cast<unsigned*>(out + FULL_OFF)[pos] = (unsigned)gidx;
            }
        }
    }
}

// ---- K2a: candidate rescore (<=4 codes), B from Btab, grid-stride waves ----
__global__ __launch_bounds__(256) void vq_resolve_cand(const float* __restrict__ z,
                                                       const float* __restrict__ e,
                                                       float* __restrict__ out) {
    const int wave = threadIdx.x >> 6, lane = threadIdx.x & 63;
    const unsigned n = *reinterpret_cast<const unsigned*>(out + CNT_OFF);
    const uint4* list = reinterpret_cast<const uint4*>(out + CAND_OFF);
    const float* Btab = out + BT_OFF;
    for (unsigned ei = blockIdx.x * 4 + wave; ei < n; ei += gridDim.x * 4) {
        uint4 ent = list[ei];
        const int gidx = (int)ent.x;
        const int c1 = (int)(ent.y & 0xFFFFu), c2 = (int)(ent.y >> 16);
        const int c3 = (int)(ent.z & 0xFFFFu), c4 = (int)(ent.z >> 16);
        const int b = gidx >> 14, m = gidx & (MB - 1);
        const float* zr = z + (size_t)b * DIM * MB + m;
        const float* e1 = e + (size_t)c1 * DIM;
        const float* e2 = e + (size_t)c2 * DIM;
        const float* e3 = e + (size_t)c3 * DIM;
        const float* e4 = e + (size_t)c4 * DIM;
        double A = 0.0;
        double d1 = 0.0, d2 = 0.0, d3 = 0.0, d4 = 0.0;
        #pragma unroll
        for (int jj = 0; jj < 4; ++jj) {
            int d = lane * 4 + jj;
            double zv = (double)zr[(size_t)d * MB];
            A = fma(zv, zv, A);
            d1 = fma(zv, (double)e1[d], d1);
            d2 = fma(zv, (double)e2[d], d2);
            d3 = fma(zv, (double)e3[d], d3);
            d4 = fma(zv, (double)e4[d], d4);
        }
        #pragma unroll
        for (int mm = 1; mm < 64; mm <<= 1) {
            A += __shfl_xor(A, mm);
            d1 += __shfl_xor(d1, mm); d2 += __shfl_xor(d2, mm);
            d3 += __shfl_xor(d3, mm); d4 += __shfl_xor(d4, mm);
        }
        if (lane == 0) {
            float Af = (float)A;
            float s1 = (Af - (float)(2.0 * d1)) + Btab[c1];
            float s2 = (Af - (float)(2.0 * d2)) + Btab[c2];
            float s3 = (Af - (float)(2.0 * d3)) + Btab[c3];
            float s4 = (Af - (float)(2.0 * d4)) + Btab[c4];
            float bv = s1; int bk = c1;
            if (lexlt(s2, c2, bv, bk)) { bv = s2; bk = c2; }
            if (lexlt(s3, c3, bv, bk)) { bv = s3; bk = c3; }
            if (lexlt(s4, c4, bv, bk)) { bv = s4; bk = c4; }
            out[IDX_OFF + gidx] = (float)bk;
        }
    }
}

// ---- K2b: full exact rescan, B from Btab, grid-stride blocks ----
__global__ __launch_bounds__(256) void vq_resolve_full(const float* __restrict__ z,
                                                       const float* __restrict__ e,
                                                       float* __restrict__ out) {
    __shared__ float zs[DIM];
    __shared__ float rv[4];
    __shared__ int ri[4];
    const int tid = threadIdx.x;
    const int wave = tid >> 6, lane = tid & 63;
    const unsigned n = reinterpret_cast<const unsigned*>(out + CNT_OFF)[1];
    const unsigned* list = reinterpret_cast<const unsigned*>(out + FULL_OFF);
    const float* Btab = out + BT_OFF;
    for (unsigned ei = blockIdx.x; ei < n; ei += gridDim.x) {
        const int gidx = (int)list[ei];
        const int b = gidx >> 14, m = gidx & (MB - 1);
        const float* zr = z + (size_t)b * DIM * MB + m;
        if (tid < DIM) zs[tid] = zr[(size_t)tid * MB];
        __syncthreads();
        double av = 0.0;
        #pragma unroll
        for (int t2 = 0; t2 < 4; ++t2) {
            double zv = (double)zs[lane * 4 + t2];
            av = fma(zv, zv, av);
        }
        #pragma unroll
        for (int mm = 1; mm < 64; mm <<= 1) av += __shfl_xor(av, mm);
        const float Af = (float)av;

        float bsv = FLT_MAX; int bsk = 0;
        for (int kk = 0; kk < 16; ++kk) {
            const int k = kk * 256 + tid;          // ascending per thread
            const float4* er4 = reinterpret_cast<const float4*>(e + (size_t)k * DIM);
            const float4* zs4 = reinterpret_cast<const float4*>(zs);
            double dot0 = 0.0, dot1 = 0.0;
            #pragma unroll 8
            for (int d4 = 0; d4 < 64; ++d4) {
                float4 ev = er4[d4];
                float4 zv = zs4[d4];
                dot0 = fma((double)zv.x, (double)ev.x, dot0);
                dot1 = fma((double)zv.y, (double)ev.y, dot1);
                dot0 = fma((double)zv.z, (double)ev.z, dot0);
                dot1 = fma((double)zv.w, (double)ev.w, dot1);
            }
            float s = (Af - (float)(2.0 * (dot0 + dot1))) + Btab[k];
            if (s < bsv) { bsv = s; bsk = k; }
        }
        #pragma unroll
        for (int mm = 1; mm < 64; mm <<= 1) {
            float ov = __shfl_xor(bsv, mm);
            int oi = __shfl_xor(bsk, mm);
            if (ov < bsv || (ov == bsv && oi < bsk)) { bsv = ov; bsk = oi; }
        }
        if (lane == 0) { rv[wave] = bsv; ri[wave] = bsk; }
        __syncthreads();
        if (tid == 0) {
            float bv = rv[0]; int bk = ri[0];
            #pragma unroll
            for (int wv = 1; wv < 4; ++wv) {
                if (rv[wv] < bv || (rv[wv] == bv && ri[wv] < bk)) { bv = rv[wv]; bk = ri[wv]; }
            }
            out[IDX_OFF + gidx] = (float)bk;
        }
        __syncthreads();
    }
}

// ---- K3: z_q scatter + fused loss; e-rows staged in LDS (R12-proven) ----
__global__ __launch_bounds__(256) void vq_apply(const float* __restrict__ z,
                                                const float* __restrict__ e,
                                                float* __restrict__ out) {
    __shared__ int lds_fi[64];
    __shared__ float lds_e[64][260];
    __shared__ double lds_ls[4];
    const int tid = threadIdx.x;
    const int wave = tid >> 6, lane = tid & 63;
    const int nbase = blockIdx.x * 64;
    const int b = nbase / MB;
    const int mbase = nbase % MB;
    if (tid < 64) lds_fi[tid] = (int)out[IDX_OFF + nbase + tid];
    __syncthreads();
    for (int r = wave; r < 64; r += 4) {
        int code = lds_fi[r];
        float4 v = reinterpret_cast<const float4*>(e + (size_t)code * DIM)[lane];
        *reinterpret_cast<float4*>(&lds_e[r][lane * 4]) = v;
    }
    __syncthreads();

    double lsum = 0.0;
    const int mloc = tid & 63;
    const int d0 = tid >> 6;
    #pragma unroll 4
    for (int d = d0; d < DIM; d += 4) {
        float ev = lds_e[mloc][d];
        size_t off = (size_t)b * (DIM * MB) + (size_t)d * MB + mbase + mloc;
        float zv = z[off];
        out[off] = ev;
        float diff = ev - zv;
        lsum += (double)diff * diff;
    }
    #pragma unroll
    for (int off = 32; off > 0; off >>= 1) lsum += __shfl_down(lsum, off);
    if (lane == 0) lds_ls[wave] = lsum;
    __syncthreads();
    if (tid == 0) {
        double t = lds_ls[0] + lds_ls[1] + lds_ls[2] + lds_ls[3];
        atomicAdd(out + LOSS_OFF, (float)(t * (1.25 / (double)ZELEMS)));
    }
}

extern "C" void kernel_launch(void* const* d_in, const int* in_sizes, int n_in,
                              void* d_out, int out_size, void* d_ws, size_t ws_size,
                              hipStream_t stream) {
    const float* z = (const float*)d_in[0];    // [4,256,16,32,32] fp32
    const float* e = (const float*)d_in[1];    // [4096,256] fp32
    float* out = (float*)d_out;

    hipMemsetAsync(out + LOSS_OFF, 0, sizeof(float), stream);
    hipMemsetAsync(out + CNT_OFF, 0, 2 * sizeof(unsigned), stream);
    vq_prep<<<1536, 256, 0, stream>>>(e, out);
    vq_fast<<<NTOT / 128, 256, 0, stream>>>(z, out);
    vq_resolve_cand<<<1024, 256, 0, stream>>>(z, e, out);
    vq_resolve_full<<<512, 256, 0, stream>>>(z, e, out);
    vq_apply<<<NTOT / 64, 256, 0, stream>>>(z, e, out);
}

// Round 21
// 427.743 us; speedup vs baseline: 1.8623x; 1.2237x over previous
//
#include <hip/hip_runtime.h>
#include <float.h>

#define KC 4096
#define DIM 256
#define MB 16384            // m per batch element (16*32*32)
#define NTOT 65536          // rows
#define ZELEMS 16777216
#define LOSS_OFF 16777216
#define IDX_OFF  16777217
// TAU: 2*(grid ULP(256)=3.05e-5) + 2*fp16-chain score err (<=4.7e-5 worst) + slack.
// Validated empirically at 1.5e-4 in R11-R20 (0 misses across 65536 rows).
#define TAU 1.5e-4f

// scratch inside z_q output region (fully overwritten by vq_apply at the end):
// [0, 524288)       fp16 e' A-fragment table (2MB)
#define BT_OFF   524288     // f32 |e_k|^2 table, 4096 floats
#define CNT_OFF  528400     // 2 uints (cand count, full count)
#define CAND_OFF 532480     // uint4 entries (16B each), cap 65536
#define FULL_OFF 800000     // uint entries, cap 65536

typedef _Float16 h8 __attribute__((ext_vector_type(8)));
typedef float f4v __attribute__((ext_vector_type(4)));

__device__ __forceinline__ bool lexlt(float av, int ai, float bv, int bi) {
    return (av < bv) || (av == bv && ai < bi);
}

// ---- P: fused prep. Blocks 0-511: fp16 e'=e*4096 A-frag table (R10-R20
// verified geometry). Blocks 512-1535: |e|^2 (fp64->f32), one wave per code. ----
__global__ __launch_bounds__(256) void vq_prep(const float* __restrict__ e,
                                               float* __restrict__ out) {
    if (blockIdx.x < 512) {
        int t = blockIdx.x * 256 + threadIdx.x;        // 0..131071
        int code = t >> 5, s8 = t & 31;
        const float4* src = reinterpret_cast<const float4*>(e + (size_t)code * DIM + s8 * 8);
        float4 v0 = src[0], v1 = src[1];
        float f[8] = {v0.x, v0.y, v0.z, v0.w, v1.x, v1.y, v1.z, v1.w};
        union { uint4 q; _Float16 h[8]; } P;
        #pragma unroll
        for (int p = 0; p < 8; ++p) P.h[p] = (_Float16)(f[p] * 4096.0f);
        int kc = s8 >> 2, khi = s8 & 3;
        int lane = khi * 16 + (code & 15);
        int slot = ((code >> 4) * 8 + kc) * 64 + lane;
        reinterpret_cast<uint4*>(out)[slot] = P.q;
    } else {
        int k = (blockIdx.x - 512) * 4 + (threadIdx.x >> 6);   // 0..4095
        int lane = threadIdx.x & 63;
        float4 v = reinterpret_cast<const float4*>(e + (size_t)k * DIM)[lane];
        double s = (double)v.x * v.x + (double)v.y * v.y + (double)v.z * v.z + (double)v.w * v.w;
        #pragma unroll
        for (int off = 32; off > 0; off >>= 1) s += __shfl_down(s, off);
        if (lane == 0) out[BT_OFF + k] = (float)s;
    }
}

// sorted insert keeping the 4 SMALLEST pushed (v0<=v1<=v2<=v3); exact-loss
// guarantee (R18-validated): any evicted value >= v3, so a lost window member
// forces v3<=thr -> n=5 -> full. No overflow counter needed.
#define INS4(V0, V1, V2, V3, L0, L1, L2, L3, v, k)                              \
    if (v < V3) {                                                               \
        if (v < V2) {                                                           \
            V3 = V2; L3 = L2;                                                   \
            if (v < V1) {                                                       \
                V2 = V1; L2 = L1;                                               \
                if (v < V0) { V1 = V0; L1 = L0; V0 = v; L0 = k; }               \
                else        { V1 = v; L1 = k; }                                 \
            } else { V2 = v; L2 = k; }                                          \
        } else { V3 = v; L3 = k; }                                              \
    }

// ---- K1: fp16 MFMA, single-pass exact-window (R18 classifier).
// Block = 64 rows (4 waves x 16 rows, ONE row-set per wave) -> 1024 blocks
// = 4 blocks/CU = 4 waves/SIMD (2x the R18/R20 wave pool). ----
__global__ __launch_bounds__(256) void vq_fast(const float* __restrict__ z,
                                               float* __restrict__ out) {
    __shared__ uint4 etile[2][512];                // 16KB double-buffered tile
    __shared__ unsigned long long lists[4][16][4]; // (wave,row,khi) packed lists
    const int tid = threadIdx.x;
    const int wave = tid >> 6, lane = tid & 63;
    const int khi = lane >> 4, l16 = lane & 15;
    const int nbase = blockIdx.x * 64;
    const int b = nbase / MB;
    const int mbase = nbase % MB;
    const float* zb = z + (size_t)b * DIM * MB + mbase + wave * 16 + l16;

    // z B-fragments (fp16), 1 row-set x 8 kc
    h8 zf[8];
    #pragma unroll
    for (int kc = 0; kc < 8; ++kc) {
        h8 va;
        #pragma unroll
        for (int j = 0; j < 8; ++j)
            va[j] = (_Float16)zb[(size_t)(kc * 32 + khi * 8 + j) * MB];
        zf[kc] = va;
    }

    const uint4* ET = reinterpret_cast<const uint4*>(out);
    const float* Btab = out + BT_OFF;

    float b1 = FLT_MAX;
    int bk = 0;
    float v0 = FLT_MAX, v1 = FLT_MAX, v2 = FLT_MAX, v3 = FLT_MAX;
    int l0 = 0, l1 = 0, l2 = 0, l3 = 0;

    uint4 r0 = ET[tid], r1 = ET[tid + 256];        // preload tile 0
    for (int tile = 0; tile < KC / 16; ++tile) {
        const int cur = tile & 1;
        etile[cur][tid] = r0; etile[cur][tid + 256] = r1;
        __syncthreads();                           // only barrier per tile
        if (tile < KC / 16 - 1) {
            r0 = ET[(size_t)(tile + 1) * 512 + tid];
            r1 = ET[(size_t)(tile + 1) * 512 + tid + 256];
        }

        // 2 independent MFMA chains (kc even/odd)
        f4v ae = {0.f, 0.f, 0.f, 0.f}, ao = ae;
        #pragma unroll
        for (int kc = 0; kc < 8; kc += 2) {
            union { uint4 q; h8 v; } afe, afo;
            afe.q = etile[cur][kc * 64 + lane];
            afo.q = etile[cur][(kc + 1) * 64 + lane];
            ae = __builtin_amdgcn_mfma_f32_16x16x32_f16(afe.v, zf[kc], ae, 0, 0, 0);
            ao = __builtin_amdgcn_mfma_f32_16x16x32_f16(afo.v, zf[kc + 1], ao, 0, 0, 0);
        }

        const f4v Bv = *reinterpret_cast<const f4v*>(Btab + tile * 16 + khi * 4);
        const int kb = tile * 16 + khi * 4;
        float sc[4];
        #pragma unroll
        for (int i = 0; i < 4; ++i)
            sc[i] = fmaf(-4.8828125e-4f, ae[i] + ao[i], Bv[i]);    // -1/2048 exact
        float m = fminf(fminf(sc[0], sc[1]), fminf(sc[2], sc[3]));
        if (m <= b1 + TAU) {                       // rare: detail insert
            #pragma unroll
            for (int i = 0; i < 4; ++i) {
                float s = sc[i]; int k = kb + i;   // ascending k per lane
                if (s < b1) {
                    if (b1 <= s + TAU) INS4(v0, v1, v2, v3, l0, l1, l2, l3, b1, bk)
                    b1 = s; bk = k;
                } else if (s <= b1 + TAU) {
                    INS4(v0, v1, v2, v3, l0, l1, l2, l3, s, k)
                }
            }
        }
    }

    // merge top-1 across the 4 khi groups (lex), keep own (b1,bk) intact
    float gb = b1;
    int gk = bk;
    #pragma unroll
    for (int off = 16; off < 64; off <<= 1) {
        float ov = __shfl_xor(gb, off); int ok = __shfl_xor(gk, off);
        if (lexlt(ov, ok, gb, gk)) { gb = ov; gk = ok; }
    }
    const float thr = gb + TAU;

    // exact-filter own entries vs FINAL threshold, pack (<=4 ks + count<=5)
    int n = 0, pa = 0, pb = 0, pc = 0, pd = 0;
    #define ADDW(kk) { if (n == 0) pa = kk; else if (n == 1) pb = kk; \
                       else if (n == 2) pc = kk; else if (n == 3) pd = kk; n++; }
    if (b1 <= thr) ADDW(bk)
    if (v0 <= thr) ADDW(l0)
    if (v1 <= thr) ADDW(l1)
    if (v2 <= thr) ADDW(l2)
    if (v3 <= thr) ADDW(l3)
    lists[wave][l16][khi] = ((unsigned long long)n << 48) |
        (unsigned long long)pa | ((unsigned long long)pb << 12) |
        ((unsigned long long)pc << 24) | ((unsigned long long)pd << 36);
    __syncthreads();

    // gather + classify + emit (lanes<16 own one row)
    unsigned* cntg = (unsigned*)(out + CNT_OFF);
    {
        bool act = (lane < 16);
        int gidx = nbase + wave * 16 + l16;
        int I1 = gk;
        int tot = 0, c[4];
        c[0] = c[1] = c[2] = c[3] = I1;            // pad with best (harmless dup)
        if (act) {
            #pragma unroll
            for (int q = 0; q < 4; ++q) {
                unsigned long long pl = lists[wave][l16][q];
                int pcnt = (int)(pl >> 48);
                #pragma unroll
                for (int j = 0; j < 4; ++j) {
                    int kv = (int)((pl >> (12 * j)) & 4095ull);
                    if (j < pcnt && tot + j < 4) c[tot + j] = kv;
                }
                tot += pcnt;
            }
            out[IDX_OFF + gidx] = (float)I1;       // final for clean; placeholder else
        }
        bool cand = act && (tot >= 2) && (tot <= 4);
        bool full = act && (tot > 4);
        unsigned long long mc = __ballot(cand);
        if (mc) {
            int leader = __ffsll((long long)mc) - 1;
            unsigned base = 0;
            if (lane == leader) base = atomicAdd(cntg, (unsigned)__popcll(mc));
            base = __shfl(base, leader);
            if (cand) {
                unsigned pos = base + (unsigned)__popcll(mc & ((1ull << lane) - 1ull));
                reinterpret_cast<uint4*>(out + CAND_OFF)[pos] =
                    make_uint4((unsigned)gidx,
                               (unsigned)c[0] | ((unsigned)c[1] << 16),
                               (unsigned)c[2] | ((unsigned)c[3] << 16), 0u);
            }
        }
        unsigned long long mf = __ballot(full);
        if (mf) {
            int leader = __ffsll((long long)mf) - 1;
            unsigned base = 0;
            if (lane == leader) base = atomicAdd(cntg + 1, (unsigned)__popcll(mf));
            base = __shfl(base, leader);
            if (full) {
                unsigned pos = base + (unsigned)__popcll(mf & ((1ull << lane) - 1ull));
                reinterpret_cast<unsigned*>(out + FULL_OFF)[pos] = (unsigned)gidx;
            }
        }
    }
}

// ---- K2a: candidate rescore (<=4 codes), B from Btab, grid-stride waves ----
__global__ __launch_bounds__(256) void vq_resolve_cand(const float* __restrict__ z,
                                                       const float* __restrict__ e,
                                                       float* __restrict__ out) {
    const int wave = threadIdx.x >> 6, lane = threadIdx.x & 63;
    const unsigned n = *reinterpret_cast<const unsigned*>(out + CNT_OFF);
    const uint4* list = reinterpret_cast<const uint4*>(out + CAND_OFF);
    const float* Btab = out + BT_OFF;
    for (unsigned ei = blockIdx.x * 4 + wave; ei < n; ei += gridDim.x * 4) {
        uint4 ent = list[ei];
        const int gidx = (int)ent.x;
        const int c1 = (int)(ent.y & 0xFFFFu), c2 = (int)(ent.y >> 16);
        const int c3 = (int)(ent.z & 0xFFFFu), c4 = (int)(ent.z >> 16);
        const int b = gidx >> 14, m = gidx & (MB - 1);
        const float* zr = z + (size_t)b * DIM * MB + m;
        const float* e1 = e + (size_t)c1 * DIM;
        const float* e2 = e + (size_t)c2 * DIM;
        const float* e3 = e + (size_t)c3 * DIM;
        const float* e4 = e + (size_t)c4 * DIM;
        double A = 0.0;
        double d1 = 0.0, d2 = 0.0, d3 = 0.0, d4 = 0.0;
        #pragma unroll
        for (int jj = 0; jj < 4; ++jj) {
            int d = lane * 4 + jj;
            double zv = (double)zr[(size_t)d * MB];
            A = fma(zv, zv, A);
            d1 = fma(zv, (double)e1[d], d1);
            d2 = fma(zv, (double)e2[d], d2);
            d3 = fma(zv, (double)e3[d], d3);
            d4 = fma(zv, (double)e4[d], d4);
        }
        #pragma unroll
        for (int mm = 1; mm < 64; mm <<= 1) {
            A += __shfl_xor(A, mm);
            d1 += __shfl_xor(d1, mm); d2 += __shfl_xor(d2, mm);
            d3 += __shfl_xor(d3, mm); d4 += __shfl_xor(d4, mm);
        }
        if (lane == 0) {
            float Af = (float)A;
            float s1 = (Af - (float)(2.0 * d1)) + Btab[c1];
            float s2 = (Af - (float)(2.0 * d2)) + Btab[c2];
            float s3 = (Af - (float)(2.0 * d3)) + Btab[c3];
            float s4 = (Af - (float)(2.0 * d4)) + Btab[c4];
            float bv = s1; int bk = c1;
            if (lexlt(s2, c2, bv, bk)) { bv = s2; bk = c2; }
            if (lexlt(s3, c3, bv, bk)) { bv = s3; bk = c3; }
            if (lexlt(s4, c4, bv, bk)) { bv = s4; bk = c4; }
            out[IDX_OFF + gidx] = (float)bk;
        }
    }
}

// ---- K2b: full exact rescan, B from Btab, grid-stride blocks ----
__global__ __launch_bounds__(256) void vq_resolve_full(const float* __restrict__ z,
                                                       const float* __restrict__ e,
                                                       float* __restrict__ out) {
    __shared__ float zs[DIM];
    __shared__ float rv[4];
    __shared__ int ri[4];
    const int tid = threadIdx.x;
    const int wave = tid >> 6, lane = tid & 63;
    const unsigned n = reinterpret_cast<const unsigned*>(out + CNT_OFF)[1];
    const unsigned* list = reinterpret_cast<const unsigned*>(out + FULL_OFF);
    const float* Btab = out + BT_OFF;
    for (unsigned ei = blockIdx.x; ei < n; ei += gridDim.x) {
        const int gidx = (int)list[ei];
        const int b = gidx >> 14, m = gidx & (MB - 1);
        const float* zr = z + (size_t)b * DIM * MB + m;
        if (tid < DIM) zs[tid] = zr[(size_t)tid * MB];
        __syncthreads();
        double av = 0.0;
        #pragma unroll
        for (int t2 = 0; t2 < 4; ++t2) {
            double zv = (double)zs[lane * 4 + t2];
            av = fma(zv, zv, av);
        }
        #pragma unroll
        for (int mm = 1; mm < 64; mm <<= 1) av += __shfl_xor(av, mm);
        const float Af = (float)av;

        float bsv = FLT_MAX; int bsk = 0;
        for (int kk = 0; kk < 16; ++kk) {
            const int k = kk * 256 + tid;          // ascending per thread
            const float4* er4 = reinterpret_cast<const float4*>(e + (size_t)k * DIM);
            const float4* zs4 = reinterpret_cast<const float4*>(zs);
            double dot0 = 0.0, dot1 = 0.0;
            #pragma unroll 8
            for (int d4 = 0; d4 < 64; ++d4) {
                float4 ev = er4[d4];
                float4 zv = zs4[d4];
                dot0 = fma((double)zv.x, (double)ev.x, dot0);
                dot1 = fma((double)zv.y, (double)ev.y, dot1);
                dot0 = fma((double)zv.z, (double)ev.z, dot0);
                dot1 = fma((double)zv.w, (double)ev.w, dot1);
            }
            float s = (Af - (float)(2.0 * (dot0 + dot1))) + Btab[k];
            if (s < bsv) { bsv = s; bsk = k; }
        }
        #pragma unroll
        for (int mm = 1; mm < 64; mm <<= 1) {
            float ov = __shfl_xor(bsv, mm);
            int oi = __shfl_xor(bsk, mm);
            if (ov < bsv || (ov == bsv && oi < bsk)) { bsv = ov; bsk = oi; }
        }
        if (lane == 0) { rv[wave] = bsv; ri[wave] = bsk; }
        __syncthreads();
        if (tid == 0) {
            float bv = rv[0]; int bk = ri[0];
            #pragma unroll
            for (int wv = 1; wv < 4; ++wv) {
                if (rv[wv] < bv || (rv[wv] == bv && ri[wv] < bk)) { bv = rv[wv]; bk = ri[wv]; }
            }
            out[IDX_OFF + gidx] = (float)bk;
        }
        __syncthreads();
    }
}

// ---- K3: z_q scatter + fused loss; e-rows staged in LDS (R12-proven) ----
__global__ __launch_bounds__(256) void vq_apply(const float* __restrict__ z,
                                                const float* __restrict__ e,
                                                float* __restrict__ out) {
    __shared__ int lds_fi[64];
    __shared__ float lds_e[64][260];
    __shared__ double lds_ls[4];
    const int tid = threadIdx.x;
    const int wave = tid >> 6, lane = tid & 63;
    const int nbase = blockIdx.x * 64;
    const int b = nbase / MB;
    const int mbase = nbase % MB;
    if (tid < 64) lds_fi[tid] = (int)out[IDX_OFF + nbase + tid];
    __syncthreads();
    for (int r = wave; r < 64; r += 4) {
        int code = lds_fi[r];
        float4 v = reinterpret_cast<const float4*>(e + (size_t)code * DIM)[lane];
        *reinterpret_cast<float4*>(&lds_e[r][lane * 4]) = v;
    }
    __syncthreads();

    double lsum = 0.0;
    const int mloc = tid & 63;
    const int d0 = tid >> 6;
    #pragma unroll 4
    for (int d = d0; d < DIM; d += 4) {
        float ev = lds_e[mloc][d];
        size_t off = (size_t)b * (DIM * MB) + (size_t)d * MB + mbase + mloc;
        float zv = z[off];
        out[off] = ev;
        float diff = ev - zv;
        lsum += (double)diff * diff;
    }
    #pragma unroll
    for (int off = 32; off > 0; off >>= 1) lsum += __shfl_down(lsum, off);
    if (lane == 0) lds_ls[wave] = lsum;
    __syncthreads();
    if (tid == 0) {
        double t = lds_ls[0] + lds_ls[1] + lds_ls[2] + lds_ls[3];
        atomicAdd(out + LOSS_OFF, (float)(t * (1.25 / (double)ZELEMS)));
    }
}

extern "C" void kernel_launch(void* const* d_in, const int* in_sizes, int n_in,
                              void* d_out, int out_size, void* d_ws, size_t ws_size,
                              hipStream_t stream) {
    const float* z = (const float*)d_in[0];    // [4,256,16,32,32] fp32
    const float* e = (const float*)d_in[1];    // [4096,256] fp32
    float* out = (float*)d_out;

    hipMemsetAsync(out + LOSS_OFF, 0, sizeof(float), stream);
    hipMemsetAsync(out + CNT_OFF, 0, 2 * sizeof(unsigned), stream);
    vq_prep<<<1536, 256, 0, stream>>>(e, out);
    vq_fast<<<NTOT / 64, 256, 0, stream>>>(z, out);
    vq_resolve_cand<<<1024, 256, 0, stream>>>(z, e, out);
    vq_resolve_full<<<512, 256, 0, stream>>>(z, e, out);
    vq_apply<<<NTOT / 64, 256, 0, stream>>>(z, e, out);
}